// Round 14
// baseline (156.626 us; speedup 1.0000x reference)
//
#include <hip/hip_runtime.h>

typedef __attribute__((ext_vector_type(8))) short short8;
typedef __attribute__((ext_vector_type(4))) float f32x4;
typedef unsigned short u16;
typedef unsigned int u32;

#define NNODES 65536
#define FDIM 128

__device__ __forceinline__ u16 f2bf(float f) {
    u32 u = __float_as_uint(f);
    u32 r = (u + 0x7fffu + ((u >> 16) & 1u)) >> 16;   // RNE
    return (u16)r;
}
__device__ __forceinline__ u32 pack2bf(float lo, float hi) {
    return ((u32)f2bf(hi) << 16) | f2bf(lo);
}
__device__ __forceinline__ float bf2f(short s) {
    return __uint_as_float(((u32)(u16)s) << 16);
}

// ---------- prep: rowptr + wT casts only ----------
__global__ void prep_kernel(const int* __restrict__ erow, int* __restrict__ rowptr,
                            const float* __restrict__ w1, u16* __restrict__ wt1,
                            const float* __restrict__ w2, u16* __restrict__ wt2,
                            const float* __restrict__ w3, u16* __restrict__ wt3,
                            int n, int e) {
    const int b = blockIdx.x;
    const int tid = threadIdx.x;
    if (b < 257) {                               // rowptr
        int r = b * 256 + tid;
        if (r > n) return;
        int lo = 0, hi = e;
        while (lo < hi) {
            int mid = (lo + hi) >> 1;
            if (erow[mid] < r) lo = mid + 1; else hi = mid;
        }
        rowptr[r] = lo;
    } else {                                     // weight transpose-cast
        const float* w; u16* wt; int idx;
        if (b < 321)      { w = w1; wt = wt1; idx = (b - 257) * 256 + tid; }
        else if (b < 385) { w = w2; wt = wt2; idx = (b - 321) * 256 + tid; }
        else              { w = w3; wt = wt3; idx = (b - 385) * 256 + tid; }
        const int K = 128;
        const int NC = (b < 385) ? 128 : 64;
        if (idx >= K * NC) return;
        int nn = idx / K, k = idx - nn * K;
        wt[idx] = f2bf(w[k * NC + nn]);
    }
}

// ---------- SpMM v7: 2 rows/wave, rounds 1 AND 2 issued upfront (8 gathers in flight) ----------
// Little's-law fix: the 27us floor was concurrency-limited (4 then 2 gathers in
// flight). Rounds 1+2 (16 edges/row, covers 96% of rows) now issue all 8
// 256B gathers back-to-back before any fma. Out-of-range slots gather row 0
// (L1-hot) with v=0. Remainder (deg>16, 0.4%) keeps the serial loop.
template<bool RELU>
__global__ __launch_bounds__(256, 6)
void spmm_kernel(const u16* __restrict__ h, const int* __restrict__ rowptr,
                 const int* __restrict__ col, const float* __restrict__ val,
                 u16* __restrict__ y, int n) {
    const int wid  = (blockIdx.x * blockDim.x + threadIdx.x) >> 6;
    const int lane = threadIdx.x & 63;
    const int rA = wid * 2;
    if (rA >= n) return;
    const int slot = lane >> 4;
    const int fg = lane & 15;

    const int sA = rowptr[rA], eA = rowptr[rA + 1], eB = rowptr[rA + 2];
    const u16* hf = h + fg * 8;

    // --- meta rounds 1+2, both rows ---
    int iA = sA + slot;
    int c0A = 0, c1A = 0, c2A = 0, c3A = 0;
    float v0A = 0.f, v1A = 0.f, v2A = 0.f, v3A = 0.f;
    if (iA < eA)      { c0A = col[iA];      v0A = val[iA]; }
    if (iA + 4 < eA)  { c1A = col[iA + 4];  v1A = val[iA + 4]; }
    if (iA + 8 < eA)  { c2A = col[iA + 8];  v2A = val[iA + 8]; }
    if (iA + 12 < eA) { c3A = col[iA + 12]; v3A = val[iA + 12]; }
    int iB = eA + slot;
    int c0B = 0, c1B = 0, c2B = 0, c3B = 0;
    float v0B = 0.f, v1B = 0.f, v2B = 0.f, v3B = 0.f;
    if (iB < eB)      { c0B = col[iB];      v0B = val[iB]; }
    if (iB + 4 < eB)  { c1B = col[iB + 4];  v1B = val[iB + 4]; }
    if (iB + 8 < eB)  { c2B = col[iB + 8];  v2B = val[iB + 8]; }
    if (iB + 12 < eB) { c3B = col[iB + 12]; v3B = val[iB + 12]; }

    // --- 8 gathers back-to-back ---
    short8 g0A = *reinterpret_cast<const short8*>(hf + (size_t)c0A * FDIM);
    short8 g1A = *reinterpret_cast<const short8*>(hf + (size_t)c1A * FDIM);
    short8 g0B = *reinterpret_cast<const short8*>(hf + (size_t)c0B * FDIM);
    short8 g1B = *reinterpret_cast<const short8*>(hf + (size_t)c1B * FDIM);
    short8 g2A = *reinterpret_cast<const short8*>(hf + (size_t)c2A * FDIM);
    short8 g3A = *reinterpret_cast<const short8*>(hf + (size_t)c3A * FDIM);
    short8 g2B = *reinterpret_cast<const short8*>(hf + (size_t)c2B * FDIM);
    short8 g3B = *reinterpret_cast<const short8*>(hf + (size_t)c3B * FDIM);

    // --- remainder meta prefetch (deg > 16, rare) ---
    int jA = iA + 16;
    int c4A = 0, c5A = 0; float v4A = 0.f, v5A = 0.f;
    if (jA < eA)     { c4A = col[jA];     v4A = val[jA]; }
    if (jA + 4 < eA) { c5A = col[jA + 4]; v5A = val[jA + 4]; }
    int jB = iB + 16;
    int c4B = 0, c5B = 0; float v4B = 0.f, v5B = 0.f;
    if (jB < eB)     { c4B = col[jB];     v4B = val[jB]; }
    if (jB + 4 < eB) { c5B = col[jB + 4]; v5B = val[jB + 4]; }

    float accA[8], accB[8];
#pragma unroll
    for (int j = 0; j < 8; ++j) { accA[j] = 0.f; accB[j] = 0.f; }

#pragma unroll
    for (int j = 0; j < 8; ++j) accA[j] = fmaf(v0A, bf2f(g0A[j]), accA[j]);
#pragma unroll
    for (int j = 0; j < 8; ++j) accA[j] = fmaf(v1A, bf2f(g1A[j]), accA[j]);
#pragma unroll
    for (int j = 0; j < 8; ++j) accB[j] = fmaf(v0B, bf2f(g0B[j]), accB[j]);
#pragma unroll
    for (int j = 0; j < 8; ++j) accB[j] = fmaf(v1B, bf2f(g1B[j]), accB[j]);
#pragma unroll
    for (int j = 0; j < 8; ++j) accA[j] = fmaf(v2A, bf2f(g2A[j]), accA[j]);
#pragma unroll
    for (int j = 0; j < 8; ++j) accA[j] = fmaf(v3A, bf2f(g3A[j]), accA[j]);
#pragma unroll
    for (int j = 0; j < 8; ++j) accB[j] = fmaf(v2B, bf2f(g2B[j]), accB[j]);
#pragma unroll
    for (int j = 0; j < 8; ++j) accB[j] = fmaf(v3B, bf2f(g3B[j]), accB[j]);

    // --- remainder rounds (deg > 16), row A then row B ---
    while (jA < eA) {
        short8 g0 = *reinterpret_cast<const short8*>(hf + (size_t)c4A * FDIM);
        short8 g1 = *reinterpret_cast<const short8*>(hf + (size_t)c5A * FDIM);
        float v0 = v4A, v1 = v5A;
        jA += 8;
        c4A = 0; c5A = 0; v4A = 0.f; v5A = 0.f;
        if (jA < eA)     { c4A = col[jA];     v4A = val[jA]; }
        if (jA + 4 < eA) { c5A = col[jA + 4]; v5A = val[jA + 4]; }
#pragma unroll
        for (int j = 0; j < 8; ++j) accA[j] = fmaf(v0, bf2f(g0[j]), accA[j]);
#pragma unroll
        for (int j = 0; j < 8; ++j) accA[j] = fmaf(v1, bf2f(g1[j]), accA[j]);
    }
    while (jB < eB) {
        short8 g0 = *reinterpret_cast<const short8*>(hf + (size_t)c4B * FDIM);
        short8 g1 = *reinterpret_cast<const short8*>(hf + (size_t)c5B * FDIM);
        float v0 = v4B, v1 = v5B;
        jB += 8;
        c4B = 0; c5B = 0; v4B = 0.f; v5B = 0.f;
        if (jB < eB)     { c4B = col[jB];     v4B = val[jB]; }
        if (jB + 4 < eB) { c5B = col[jB + 4]; v5B = val[jB + 4]; }
#pragma unroll
        for (int j = 0; j < 8; ++j) accB[j] = fmaf(v0, bf2f(g0[j]), accB[j]);
#pragma unroll
        for (int j = 0; j < 8; ++j) accB[j] = fmaf(v1, bf2f(g1[j]), accB[j]);
    }

#pragma unroll
    for (int m = 16; m <= 32; m <<= 1) {
#pragma unroll
        for (int j = 0; j < 8; ++j) {
            accA[j] += __shfl_xor(accA[j], m, 64);
            accB[j] += __shfl_xor(accB[j], m, 64);
        }
    }

    float a0 = 0.f, a1 = 0.f, b0 = 0.f, b1 = 0.f;
#pragma unroll
    for (int ss = 0; ss < 4; ++ss)
        if (slot == ss) {
            a0 = accA[ss * 2]; a1 = accA[ss * 2 + 1];
            b0 = accB[ss * 2]; b1 = accB[ss * 2 + 1];
        }
    if (RELU) {
        a0 = fmaxf(a0, 0.f); a1 = fmaxf(a1, 0.f);
        b0 = fmaxf(b0, 0.f); b1 = fmaxf(b1, 0.f);
    }
    *reinterpret_cast<u32*>(y + (size_t)rA * FDIM + fg * 8 + slot * 2) = pack2bf(a0, a1);
    *reinterpret_cast<u32*>(y + (size_t)(rA + 1) * FDIM + fg * 8 + slot * 2) = pack2bf(b0, b1);
}

// ---------- GEMM: LDS-staged weights, one 16-row chunk per wave ----------
template<int NT, bool RELU, bool OUT_BF16, bool FP32A>
__global__ __launch_bounds__(256, 4)
void gemm_kernel(const void* __restrict__ Av, const u16* __restrict__ WT,
                 void* __restrict__ out, int M) {
    constexpr int NC = NT * 16;
    constexpr int LSTR = 136;                 // u16: 128 data + 8 pad
    __shared__ u16 wlds[NC * LSTR];

    const int t = threadIdx.x;
    const int fr = t & 15;
#pragma unroll
    for (int n = t >> 4; n < NC; n += 16)
        *reinterpret_cast<uint4*>(&wlds[n * LSTR + fr * 8]) =
            *reinterpret_cast<const uint4*>(&WT[(size_t)n * 128 + fr * 8]);
    __syncthreads();

    const int lane = t & 63;
    const int dn = lane & 15;
    const int kg = lane >> 4;
    const int r0 = (blockIdx.x * 4 + (t >> 6)) << 4;
    if (r0 >= M) return;

    f32x4 acc[NT];
#pragma unroll
    for (int nt = 0; nt < NT; ++nt) acc[nt] = (f32x4){0.f, 0.f, 0.f, 0.f};

#pragma unroll
    for (int s = 0; s < 4; ++s) {
        short8 a;
        if (FP32A) {
            const float* Af = (const float*)Av + (size_t)(r0 + dn) * 128 + s * 32 + kg * 8;
            float4 x0 = *reinterpret_cast<const float4*>(Af);
            float4 x1 = *reinterpret_cast<const float4*>(Af + 4);
            a[0] = (short)f2bf(x0.x); a[1] = (short)f2bf(x0.y);
            a[2] = (short)f2bf(x0.z); a[3] = (short)f2bf(x0.w);
            a[4] = (short)f2bf(x1.x); a[5] = (short)f2bf(x1.y);
            a[6] = (short)f2bf(x1.z); a[7] = (short)f2bf(x1.w);
        } else {
            a = *reinterpret_cast<const short8*>(
                (const u16*)Av + (size_t)(r0 + dn) * 128 + s * 32 + kg * 8);
        }
#pragma unroll
        for (int nt = 0; nt < NT; ++nt) {
            short8 b = *reinterpret_cast<const short8*>(
                &wlds[(nt * 16 + dn) * LSTR + s * 32 + kg * 8]);
            acc[nt] = __builtin_amdgcn_mfma_f32_16x16x32_bf16(b, a, acc[nt], 0, 0, 0);
        }
    }

    const int row = r0 + dn;
#pragma unroll
    for (int nt = 0; nt < NT; ++nt) {
        float v0 = acc[nt][0], v1 = acc[nt][1], v2 = acc[nt][2], v3 = acc[nt][3];
        if (RELU) {
            v0 = fmaxf(v0, 0.f); v1 = fmaxf(v1, 0.f);
            v2 = fmaxf(v2, 0.f); v3 = fmaxf(v3, 0.f);
        }
        if (OUT_BF16) {
            uint2 p; p.x = pack2bf(v0, v1); p.y = pack2bf(v2, v3);
            *reinterpret_cast<uint2*>(
                (u16*)out + (size_t)row * NC + nt * 16 + kg * 4) = p;
        } else {
            float4 p = make_float4(v0, v1, v2, v3);
            *reinterpret_cast<float4*>(
                (float*)out + (size_t)row * NC + nt * 16 + kg * 4) = p;
        }
    }
}

// ---------- Fused GEMM2+GEMM3: out = relu(Y @ W2) @ W3, no h2 round-trip ----------
__global__ __launch_bounds__(256, 3)
void gemm23_kernel(const u16* __restrict__ A, const u16* __restrict__ WT2,
                   const u16* __restrict__ WT3, float* __restrict__ out, int M) {
    constexpr int LSTR = 136;
    __shared__ u16 w2l[128 * LSTR];           // 34816 B
    __shared__ u16 h2l[4][16 * LSTR];         // 17408 B (4.3KB per wave, private)

    const int t = threadIdx.x;
    const int fr = t & 15;
#pragma unroll
    for (int n = t >> 4; n < 128; n += 16)
        *reinterpret_cast<uint4*>(&w2l[n * LSTR + fr * 8]) =
            *reinterpret_cast<const uint4*>(&WT2[(size_t)n * 128 + fr * 8]);

    const int wave = t >> 6;
    const int lane = t & 63;
    const int dn = lane & 15;
    const int kg = lane >> 4;

    short8 bw3[4][4];
#pragma unroll
    for (int nt = 0; nt < 4; ++nt)
#pragma unroll
        for (int s = 0; s < 4; ++s)
            bw3[nt][s] = *reinterpret_cast<const short8*>(
                &WT3[(size_t)(nt * 16 + dn) * 128 + s * 32 + kg * 8]);

    __syncthreads();

    const int r0 = (blockIdx.x * 4 + wave) << 4;
    if (r0 >= M) return;

    f32x4 acc2[8];
#pragma unroll
    for (int nt = 0; nt < 8; ++nt) acc2[nt] = (f32x4){0.f, 0.f, 0.f, 0.f};
#pragma unroll
    for (int s = 0; s < 4; ++s) {
        short8 a = *reinterpret_cast<const short8*>(
            &A[(size_t)(r0 + dn) * 128 + s * 32 + kg * 8]);
#pragma unroll
        for (int nt = 0; nt < 8; ++nt) {
            short8 b = *reinterpret_cast<const short8*>(
                &w2l[(nt * 16 + dn) * LSTR + s * 32 + kg * 8]);
            acc2[nt] = __builtin_amdgcn_mfma_f32_16x16x32_bf16(b, a, acc2[nt], 0, 0, 0);
        }
    }

    u16* my = h2l[wave];
#pragma unroll
    for (int nt = 0; nt < 8; ++nt) {
        float v0 = fmaxf(acc2[nt][0], 0.f), v1 = fmaxf(acc2[nt][1], 0.f);
        float v2 = fmaxf(acc2[nt][2], 0.f), v3 = fmaxf(acc2[nt][3], 0.f);
        uint2 p; p.x = pack2bf(v0, v1); p.y = pack2bf(v2, v3);
        *reinterpret_cast<uint2*>(&my[dn * LSTR + nt * 16 + kg * 4]) = p;
    }

    f32x4 acc3[4];
#pragma unroll
    for (int nt = 0; nt < 4; ++nt) acc3[nt] = (f32x4){0.f, 0.f, 0.f, 0.f};
#pragma unroll
    for (int s = 0; s < 4; ++s) {
        short8 a = *reinterpret_cast<const short8*>(
            &my[dn * LSTR + s * 32 + kg * 8]);
#pragma unroll
        for (int nt = 0; nt < 4; ++nt)
            acc3[nt] = __builtin_amdgcn_mfma_f32_16x16x32_bf16(bw3[nt][s], a, acc3[nt], 0, 0, 0);
    }

    const int row = r0 + dn;
#pragma unroll
    for (int nt = 0; nt < 4; ++nt)
        *reinterpret_cast<float4*>(out + (size_t)row * 64 + nt * 16 + kg * 4) =
            make_float4(acc3[nt][0], acc3[nt][1], acc3[nt][2], acc3[nt][3]);
}

extern "C" void kernel_launch(void* const* d_in, const int* in_sizes, int n_in,
                              void* d_out, int out_size, void* d_ws, size_t ws_size,
                              hipStream_t stream) {
    const float* x    = (const float*)d_in[0];
    const float* w1   = (const float*)d_in[1];
    const float* w2   = (const float*)d_in[2];
    const float* w3   = (const float*)d_in[3];
    const int*   erow = (const int*)d_in[4];
    const int*   ecol = (const int*)d_in[5];
    const float* eval = (const float*)d_in[6];
    float* out = (float*)d_out;

    const int N = in_sizes[0] / FDIM;
    const int E = in_sizes[4];

    char* ws = (char*)d_ws;
    int* rowptr = (int*)ws;                                  // (N+1)*4
    u16* wt1 = (u16*)(ws + (512 << 10));                     // 32KB
    u16* wt2 = wt1 + 128 * 128;                              // 32KB
    u16* wt3 = wt2 + 128 * 128;                              // 16KB
    u16* zbuf = (u16*)(ws + (1 << 20));                      // 16MB bf16 [N][128]
    u16* hbuf = (u16*)(ws + (18u << 20));                    // 16MB bf16 [N][128]

    prep_kernel<<<417, 256, 0, stream>>>(erow, rowptr, w1, wt1, w2, wt2, w3, wt3, N, E);
    // z = x @ W1 (fp32 A direct; linearity: spmm(x)@W1 == spmm(x@W1))
    gemm_kernel<8, false, true, true><<<N / 64, 256, 0, stream>>>(x, wt1, zbuf, N);
    // h1 = relu(spmm(z))
    spmm_kernel<true><<<N / 8, 256, 0, stream>>>(zbuf, rowptr, ecol, eval, hbuf, N);
    // y = spmm(h1)
    spmm_kernel<false><<<N / 8, 256, 0, stream>>>(hbuf, rowptr, ecol, eval, zbuf, N);
    // out = relu(y @ W2) @ W3
    gemm23_kernel<<<N / 64, 256, 0, stream>>>(zbuf, wt2, wt3, out, N);
}

// Round 15
// 88.632 us; speedup vs baseline: 1.7671x; 1.7671x over previous
//
#include <hip/hip_runtime.h>

typedef __attribute__((ext_vector_type(8))) short short8;
typedef __attribute__((ext_vector_type(4))) float f32x4;
typedef unsigned short u16;
typedef unsigned int u32;

#define NNODES 65536
#define FDIM 128

__device__ __forceinline__ u16 f2bf(float f) {
    u32 u = __float_as_uint(f);
    u32 r = (u + 0x7fffu + ((u >> 16) & 1u)) >> 16;   // RNE
    return (u16)r;
}
__device__ __forceinline__ u32 pack2bf(float lo, float hi) {
    return ((u32)f2bf(hi) << 16) | f2bf(lo);
}

// ---------- prep: rowptr + wT casts only ----------
__global__ void prep_kernel(const int* __restrict__ erow, int* __restrict__ rowptr,
                            const float* __restrict__ w1, u16* __restrict__ wt1,
                            const float* __restrict__ w2, u16* __restrict__ wt2,
                            const float* __restrict__ w3, u16* __restrict__ wt3,
                            int n, int e) {
    const int b = blockIdx.x;
    const int tid = threadIdx.x;
    if (b < 257) {                               // rowptr
        int r = b * 256 + tid;
        if (r > n) return;
        int lo = 0, hi = e;
        while (lo < hi) {
            int mid = (lo + hi) >> 1;
            if (erow[mid] < r) lo = mid + 1; else hi = mid;
        }
        rowptr[r] = lo;
    } else {                                     // weight transpose-cast
        const float* w; u16* wt; int idx;
        if (b < 321)      { w = w1; wt = wt1; idx = (b - 257) * 256 + tid; }
        else if (b < 385) { w = w2; wt = wt2; idx = (b - 321) * 256 + tid; }
        else              { w = w3; wt = wt3; idx = (b - 385) * 256 + tid; }
        const int K = 128;
        const int NC = (b < 385) ? 128 : 64;
        if (idx >= K * NC) return;
        int nn = idx / K, k = idx - nn * K;
        wt[idx] = f2bf(w[k * NC + nn]);
    }
}

// ---------- SpMM v8: 1 row/wave, lane = 2 features, scalar meta, 1-VGPR gathers ----------
// R13 lesson: gather PAYLOAD registers were the spill bomb (8 x short8 = 32
// VGPR). Here a gather is the whole 256B row spread over 64 lanes -> payload
// 1 VGPR each. Edge meta col/val[s..s+16] is wave-uniform (readfirstlane'd row)
// -> s_load into SGPRs: no shuffles, no butterfly, acc = 2 regs. Up to 16
// gathers issued back-to-back (deg tiers 8/16 are wave-uniform branches);
// serial 2-wide tail for deg>16 (rare). Coalesced 4B/lane store (+fused relu).
template<bool RELU>
__global__ __launch_bounds__(256, 8)
void spmm_kernel(const u16* __restrict__ h, const int* __restrict__ rowptr,
                 const int* __restrict__ col, const float* __restrict__ val,
                 u16* __restrict__ y, int n) {
    const int lane = threadIdx.x & 63;
    int r = __builtin_amdgcn_readfirstlane((int)((blockIdx.x * blockDim.x + threadIdx.x) >> 6));
    if (r >= n) return;
    const int s = rowptr[r], e = rowptr[r + 1];   // uniform -> s_load
    const int deg = e - s;
    const u16* hl = h + lane * 2;

    float a0 = 0.f, a1 = 0.f;

    if (deg <= 8) {
        int   cc[8]; float vv[8];
#pragma unroll
        for (int j = 0; j < 8; ++j) {
            bool ok = j < deg;
            cc[j] = ok ? col[s + j] : 0;
            vv[j] = ok ? val[s + j] : 0.f;
        }
        u32 g[8];
#pragma unroll
        for (int j = 0; j < 8; ++j)
            g[j] = *reinterpret_cast<const u32*>(hl + (size_t)cc[j] * FDIM);
#pragma unroll
        for (int j = 0; j < 8; ++j) {
            a0 = fmaf(vv[j], __uint_as_float(g[j] << 16), a0);
            a1 = fmaf(vv[j], __uint_as_float(g[j] & 0xffff0000u), a1);
        }
    } else {
        int   cc[16]; float vv[16];
#pragma unroll
        for (int j = 0; j < 16; ++j) {
            bool ok = j < deg;
            cc[j] = ok ? col[s + j] : 0;
            vv[j] = ok ? val[s + j] : 0.f;
        }
        u32 g[16];
#pragma unroll
        for (int j = 0; j < 16; ++j)
            g[j] = *reinterpret_cast<const u32*>(hl + (size_t)cc[j] * FDIM);
#pragma unroll
        for (int j = 0; j < 16; ++j) {
            a0 = fmaf(vv[j], __uint_as_float(g[j] << 16), a0);
            a1 = fmaf(vv[j], __uint_as_float(g[j] & 0xffff0000u), a1);
        }
        // serial 2-wide tail (deg > 16, rare)
        int j = s + 16;
        while (j < e) {
            int  c0 = col[j];     float v0 = val[j];
            bool ok1 = j + 1 < e;
            int  c1 = ok1 ? col[j + 1] : 0;
            float v1 = ok1 ? val[j + 1] : 0.f;
            u32 g0 = *reinterpret_cast<const u32*>(hl + (size_t)c0 * FDIM);
            u32 g1 = *reinterpret_cast<const u32*>(hl + (size_t)c1 * FDIM);
            a0 = fmaf(v0, __uint_as_float(g0 << 16), a0);
            a1 = fmaf(v0, __uint_as_float(g0 & 0xffff0000u), a1);
            a0 = fmaf(v1, __uint_as_float(g1 << 16), a0);
            a1 = fmaf(v1, __uint_as_float(g1 & 0xffff0000u), a1);
            j += 2;
        }
    }

    if (RELU) { a0 = fmaxf(a0, 0.f); a1 = fmaxf(a1, 0.f); }
    *reinterpret_cast<u32*>(y + (size_t)r * FDIM + lane * 2) = pack2bf(a0, a1);
}

// ---------- GEMM: LDS-staged weights, one 16-row chunk per wave ----------
template<int NT, bool RELU, bool OUT_BF16, bool FP32A>
__global__ __launch_bounds__(256, 4)
void gemm_kernel(const void* __restrict__ Av, const u16* __restrict__ WT,
                 void* __restrict__ out, int M) {
    constexpr int NC = NT * 16;
    constexpr int LSTR = 136;                 // u16: 128 data + 8 pad
    __shared__ u16 wlds[NC * LSTR];

    const int t = threadIdx.x;
    const int fr = t & 15;
#pragma unroll
    for (int n = t >> 4; n < NC; n += 16)
        *reinterpret_cast<uint4*>(&wlds[n * LSTR + fr * 8]) =
            *reinterpret_cast<const uint4*>(&WT[(size_t)n * 128 + fr * 8]);
    __syncthreads();

    const int lane = t & 63;
    const int dn = lane & 15;
    const int kg = lane >> 4;
    const int r0 = (blockIdx.x * 4 + (t >> 6)) << 4;
    if (r0 >= M) return;

    f32x4 acc[NT];
#pragma unroll
    for (int nt = 0; nt < NT; ++nt) acc[nt] = (f32x4){0.f, 0.f, 0.f, 0.f};

#pragma unroll
    for (int s = 0; s < 4; ++s) {
        short8 a;
        if (FP32A) {
            const float* Af = (const float*)Av + (size_t)(r0 + dn) * 128 + s * 32 + kg * 8;
            float4 x0 = *reinterpret_cast<const float4*>(Af);
            float4 x1 = *reinterpret_cast<const float4*>(Af + 4);
            a[0] = (short)f2bf(x0.x); a[1] = (short)f2bf(x0.y);
            a[2] = (short)f2bf(x0.z); a[3] = (short)f2bf(x0.w);
            a[4] = (short)f2bf(x1.x); a[5] = (short)f2bf(x1.y);
            a[6] = (short)f2bf(x1.z); a[7] = (short)f2bf(x1.w);
        } else {
            a = *reinterpret_cast<const short8*>(
                (const u16*)Av + (size_t)(r0 + dn) * 128 + s * 32 + kg * 8);
        }
#pragma unroll
        for (int nt = 0; nt < NT; ++nt) {
            short8 b = *reinterpret_cast<const short8*>(
                &wlds[(nt * 16 + dn) * LSTR + s * 32 + kg * 8]);
            acc[nt] = __builtin_amdgcn_mfma_f32_16x16x32_bf16(b, a, acc[nt], 0, 0, 0);
        }
    }

    const int row = r0 + dn;
#pragma unroll
    for (int nt = 0; nt < NT; ++nt) {
        float v0 = acc[nt][0], v1 = acc[nt][1], v2 = acc[nt][2], v3 = acc[nt][3];
        if (RELU) {
            v0 = fmaxf(v0, 0.f); v1 = fmaxf(v1, 0.f);
            v2 = fmaxf(v2, 0.f); v3 = fmaxf(v3, 0.f);
        }
        if (OUT_BF16) {
            uint2 p; p.x = pack2bf(v0, v1); p.y = pack2bf(v2, v3);
            *reinterpret_cast<uint2*>(
                (u16*)out + (size_t)row * NC + nt * 16 + kg * 4) = p;
        } else {
            float4 p = make_float4(v0, v1, v2, v3);
            *reinterpret_cast<float4*>(
                (float*)out + (size_t)row * NC + nt * 16 + kg * 4) = p;
        }
    }
}

// ---------- Fused GEMM2+GEMM3: out = relu(Y @ W2) @ W3, no h2 round-trip ----------
__global__ __launch_bounds__(256, 2)
void gemm23_kernel(const u16* __restrict__ A, const u16* __restrict__ WT2,
                   const u16* __restrict__ WT3, float* __restrict__ out, int M) {
    constexpr int LSTR = 136;
    __shared__ u16 w2l[128 * LSTR];           // 34816 B
    __shared__ u16 h2l[4][16 * LSTR];         // 17408 B (4.3KB per wave, private)

    const int t = threadIdx.x;
    const int fr = t & 15;
#pragma unroll
    for (int n = t >> 4; n < 128; n += 16)
        *reinterpret_cast<uint4*>(&w2l[n * LSTR + fr * 8]) =
            *reinterpret_cast<const uint4*>(&WT2[(size_t)n * 128 + fr * 8]);

    const int wave = t >> 6;
    const int lane = t & 63;
    const int dn = lane & 15;
    const int kg = lane >> 4;

    short8 bw3[4][4];
#pragma unroll
    for (int nt = 0; nt < 4; ++nt)
#pragma unroll
        for (int s = 0; s < 4; ++s)
            bw3[nt][s] = *reinterpret_cast<const short8*>(
                &WT3[(size_t)(nt * 16 + dn) * 128 + s * 32 + kg * 8]);

    __syncthreads();

    const int r0 = (blockIdx.x * 4 + wave) << 4;
    if (r0 >= M) return;

    f32x4 acc2[8];
#pragma unroll
    for (int nt = 0; nt < 8; ++nt) acc2[nt] = (f32x4){0.f, 0.f, 0.f, 0.f};
#pragma unroll
    for (int s = 0; s < 4; ++s) {
        short8 a = *reinterpret_cast<const short8*>(
            &A[(size_t)(r0 + dn) * 128 + s * 32 + kg * 8]);
#pragma unroll
        for (int nt = 0; nt < 8; ++nt) {
            short8 b = *reinterpret_cast<const short8*>(
                &w2l[(nt * 16 + dn) * LSTR + s * 32 + kg * 8]);
            acc2[nt] = __builtin_amdgcn_mfma_f32_16x16x32_bf16(b, a, acc2[nt], 0, 0, 0);
        }
    }

    u16* my = h2l[wave];
#pragma unroll
    for (int nt = 0; nt < 8; ++nt) {
        float v0 = fmaxf(acc2[nt][0], 0.f), v1 = fmaxf(acc2[nt][1], 0.f);
        float v2 = fmaxf(acc2[nt][2], 0.f), v3 = fmaxf(acc2[nt][3], 0.f);
        uint2 p; p.x = pack2bf(v0, v1); p.y = pack2bf(v2, v3);
        *reinterpret_cast<uint2*>(&my[dn * LSTR + nt * 16 + kg * 4]) = p;
    }

    f32x4 acc3[4];
#pragma unroll
    for (int nt = 0; nt < 4; ++nt) acc3[nt] = (f32x4){0.f, 0.f, 0.f, 0.f};
#pragma unroll
    for (int s = 0; s < 4; ++s) {
        short8 a = *reinterpret_cast<const short8*>(
            &my[dn * LSTR + s * 32 + kg * 8]);
#pragma unroll
        for (int nt = 0; nt < 4; ++nt)
            acc3[nt] = __builtin_amdgcn_mfma_f32_16x16x32_bf16(bw3[nt][s], a, acc3[nt], 0, 0, 0);
    }

    const int row = r0 + dn;
#pragma unroll
    for (int nt = 0; nt < 4; ++nt)
        *reinterpret_cast<float4*>(out + (size_t)row * 64 + nt * 16 + kg * 4) =
            make_float4(acc3[nt][0], acc3[nt][1], acc3[nt][2], acc3[nt][3]);
}

extern "C" void kernel_launch(void* const* d_in, const int* in_sizes, int n_in,
                              void* d_out, int out_size, void* d_ws, size_t ws_size,
                              hipStream_t stream) {
    const float* x    = (const float*)d_in[0];
    const float* w1   = (const float*)d_in[1];
    const float* w2   = (const float*)d_in[2];
    const float* w3   = (const float*)d_in[3];
    const int*   erow = (const int*)d_in[4];
    const int*   ecol = (const int*)d_in[5];
    const float* eval = (const float*)d_in[6];
    float* out = (float*)d_out;

    const int N = in_sizes[0] / FDIM;
    const int E = in_sizes[4];

    char* ws = (char*)d_ws;
    int* rowptr = (int*)ws;                                  // (N+1)*4
    u16* wt1 = (u16*)(ws + (512 << 10));                     // 32KB
    u16* wt2 = wt1 + 128 * 128;                              // 32KB
    u16* wt3 = wt2 + 128 * 128;                              // 16KB
    u16* zbuf = (u16*)(ws + (1 << 20));                      // 16MB bf16 [N][128]
    u16* hbuf = (u16*)(ws + (18u << 20));                    // 16MB bf16 [N][128]

    prep_kernel<<<417, 256, 0, stream>>>(erow, rowptr, w1, wt1, w2, wt2, w3, wt3, N, E);
    // z = x @ W1 (fp32 A direct; linearity: spmm(x)@W1 == spmm(x@W1))
    gemm_kernel<8, false, true, true><<<N / 64, 256, 0, stream>>>(x, wt1, zbuf, N);
    // h1 = relu(spmm(z))
    spmm_kernel<true><<<N / 4, 256, 0, stream>>>(zbuf, rowptr, ecol, eval, hbuf, N);
    // y = spmm(h1)
    spmm_kernel<false><<<N / 4, 256, 0, stream>>>(hbuf, rowptr, ecol, eval, zbuf, N);
    // out = relu(y @ W2) @ W3
    gemm23_kernel<<<N / 64, 256, 0, stream>>>(zbuf, wt2, wt3, out, N);
}